// Round 3
// baseline (367.459 us; speedup 1.0000x reference)
//
#include <hip/hip_runtime.h>
#include <math.h>

// peak_map [256, 131072] f32, scalar logit_thresh.
// Outputs concatenated: smooth_peaks [256*131072] f32, peak_mask [256*131072] f32 (0/1).
#define ROWS 256
#define COLS 131072
#define SHARP 10.0f
#define EPT 8                 // elements per thread
#define TPR (COLS / EPT)      // 16384 = 2^14 threads per row

typedef float vf4 __attribute__((ext_vector_type(4)));  // clang-native, OK for nontemporal builtins

__global__ __launch_bounds__(256) void peak_extract_kernel(
    const float* __restrict__ x,
    const float* __restrict__ logit_thresh,
    float* __restrict__ smooth,
    float* __restrict__ mask)
{
    const float thresh = 1.0f / (1.0f + expf(-logit_thresh[0]));

    const long long gid = (long long)blockIdx.x * blockDim.x + threadIdx.x;
    const int row = (int)(gid >> 14);          // 2^14 threads per row
    const int col = ((int)gid & (TPR - 1)) << 3;

    const float* __restrict__ xr = x + (long long)row * COLS;

    // window needs elements [col-2, col+9]; v[k] = xr[col-2+k] with edge clamp
    float v[12];
    const vf4 a = *(const vf4*)(xr + col);
    const vf4 b = *(const vf4*)(xr + col + 4);
    v[2] = a.x; v[3] = a.y; v[4] = a.z; v[5] = a.w;
    v[6] = b.x; v[7] = b.y; v[8] = b.z; v[9] = b.w;
    v[0]  = xr[max(col - 2, 0)];
    v[1]  = xr[max(col - 1, 0)];
    v[10] = xr[min(col + 8, COLS - 1)];
    v[11] = xr[min(col + 9, COLS - 1)];

    float s_out[EPT], m_out[EPT];
#pragma unroll
    for (int k = 0; k < EPT; ++k) {
        float p = v[k];
        p = fmaxf(p, v[k + 1]);
        p = fmaxf(p, v[k + 2]);
        p = fmaxf(p, v[k + 3]);
        p = fmaxf(p, v[k + 4]);
        const float xv   = v[k + 2];
        const float gate = 1.0f / (1.0f + expf(-SHARP * (xv - thresh)));
        const float lm   = 1.0f / (1.0f + expf(-SHARP * (xv - p)));
        const float s    = xv * gate * lm;
        s_out[k] = s;
        m_out[k] = (s >= thresh) ? 1.0f : 0.0f;
    }

    const long long base = (long long)row * COLS + col;
    vf4 s0 = { s_out[0], s_out[1], s_out[2], s_out[3] };
    vf4 s1 = { s_out[4], s_out[5], s_out[6], s_out[7] };
    vf4 m0 = { m_out[0], m_out[1], m_out[2], m_out[3] };
    vf4 m1 = { m_out[4], m_out[5], m_out[6], m_out[7] };

    // write-once outputs: bypass cache so input halo reuse keeps L1/L2
    __builtin_nontemporal_store(s0, (vf4*)(smooth + base));
    __builtin_nontemporal_store(s1, (vf4*)(smooth + base + 4));
    __builtin_nontemporal_store(m0, (vf4*)(mask + base));
    __builtin_nontemporal_store(m1, (vf4*)(mask + base + 4));
}

extern "C" void kernel_launch(void* const* d_in, const int* in_sizes, int n_in,
                              void* d_out, int out_size, void* d_ws, size_t ws_size,
                              hipStream_t stream) {
    const float* x            = (const float*)d_in[0];
    const float* logit_thresh = (const float*)d_in[1];

    float* smooth = (float*)d_out;
    float* mask   = (float*)d_out + (long long)ROWS * COLS;

    const long long n_thread = (long long)ROWS * COLS / EPT;  // 4,194,304
    const int block = 256;
    const int grid  = (int)(n_thread / block);                // 16,384

    peak_extract_kernel<<<grid, block, 0, stream>>>(x, logit_thresh, smooth, mask);
}

// Round 4
// 362.129 us; speedup vs baseline: 1.0147x; 1.0147x over previous
//
#include <hip/hip_runtime.h>
#include <math.h>

// peak_map [256, 131072] f32, scalar logit_thresh.
// Outputs concatenated: smooth_peaks [256*131072] f32, peak_mask [256*131072] f32 (0/1).
#define ROWS 256
#define COLS 131072
#define SHARP 10.0f
#define EPT 8                 // elements per thread
#define TPR (COLS / EPT)      // 16384 = 2^14 threads per row

typedef float vf4 __attribute__((ext_vector_type(4)));

__global__ __launch_bounds__(256) void peak_extract_kernel(
    const float* __restrict__ x,
    const float* __restrict__ logit_thresh,
    float* __restrict__ smooth,
    float* __restrict__ mask)
{
    const float thresh = 1.0f / (1.0f + expf(-logit_thresh[0]));

    // grid*block = 4,194,304 < 2^31: 32-bit index math is safe
    const int gid = blockIdx.x * blockDim.x + threadIdx.x;
    const int row = gid >> 14;                 // 2^14 threads per row
    const int col = (gid & (TPR - 1)) << 3;

    const float* __restrict__ xr = x + (long long)row * COLS;

    // window needs elements [col-2, col+9]; v[k] = xr[col-2+k] with edge clamp
    float v[12];
    const vf4 a = *(const vf4*)(xr + col);
    const vf4 b = *(const vf4*)(xr + col + 4);
    v[2] = a.x; v[3] = a.y; v[4] = a.z; v[5] = a.w;
    v[6] = b.x; v[7] = b.y; v[8] = b.z; v[9] = b.w;
    v[0]  = xr[max(col - 2, 0)];
    v[1]  = xr[max(col - 1, 0)];
    v[10] = xr[min(col + 8, COLS - 1)];
    v[11] = xr[min(col + 9, COLS - 1)];

    float s_out[EPT], m_out[EPT];
#pragma unroll
    for (int k = 0; k < EPT; ++k) {
        float p = v[k];
        p = fmaxf(p, v[k + 1]);
        p = fmaxf(p, v[k + 2]);
        p = fmaxf(p, v[k + 3]);
        p = fmaxf(p, v[k + 4]);
        const float xv   = v[k + 2];
        const float gate = 1.0f / (1.0f + expf(-SHARP * (xv - thresh)));
        const float lm   = 1.0f / (1.0f + expf(-SHARP * (xv - p)));
        const float s    = xv * gate * lm;
        s_out[k] = s;
        m_out[k] = (s >= thresh) ? 1.0f : 0.0f;
    }

    const long long base = (long long)row * COLS + col;
    // regular cached stores (NT variant regressed 352->367 us in R3)
    *(vf4*)(smooth + base)     = (vf4){ s_out[0], s_out[1], s_out[2], s_out[3] };
    *(vf4*)(smooth + base + 4) = (vf4){ s_out[4], s_out[5], s_out[6], s_out[7] };
    *(vf4*)(mask + base)       = (vf4){ m_out[0], m_out[1], m_out[2], m_out[3] };
    *(vf4*)(mask + base + 4)   = (vf4){ m_out[4], m_out[5], m_out[6], m_out[7] };
}

extern "C" void kernel_launch(void* const* d_in, const int* in_sizes, int n_in,
                              void* d_out, int out_size, void* d_ws, size_t ws_size,
                              hipStream_t stream) {
    const float* x            = (const float*)d_in[0];
    const float* logit_thresh = (const float*)d_in[1];

    float* smooth = (float*)d_out;
    float* mask   = (float*)d_out + (long long)ROWS * COLS;

    const long long n_thread = (long long)ROWS * COLS / EPT;  // 4,194,304
    const int block = 256;
    const int grid  = (int)(n_thread / block);                // 16,384

    peak_extract_kernel<<<grid, block, 0, stream>>>(x, logit_thresh, smooth, mask);
}

// Round 5
// 353.059 us; speedup vs baseline: 1.0408x; 1.0257x over previous
//
#include <hip/hip_runtime.h>
#include <math.h>

// peak_map [256, 131072] f32, scalar logit_thresh.
// Outputs concatenated: smooth_peaks [256*131072] f32, peak_mask [256*131072] f32 (0/1).
//
// Config notes (measured, MI355X):
//   EPT=4 + cached stores : 352 us  <- best (this file)
//   EPT=8 + cached stores : 362 us  (fewer waves -> worse latency hiding)
//   EPT=8 + NT stores     : 367 us  (nt de-allocation hurts write path)
// ~250 us of dur_us is harness reset traffic (1 GiB ws fill + d_out poison +
// input restore); kernel portion ~90-100 us vs ~63-73 us mixed-stream BW floor.
#define ROWS 256
#define COLS 131072
#define SHARP 10.0f

typedef float vf4 __attribute__((ext_vector_type(4)));

// Each thread handles 4 contiguous elements of one row. 2^15 threads/row.
__global__ __launch_bounds__(256) void peak_extract_kernel(
    const float* __restrict__ x,
    const float* __restrict__ logit_thresh,
    float* __restrict__ smooth,
    float* __restrict__ mask)
{
    const float thresh = 1.0f / (1.0f + expf(-logit_thresh[0]));

    // grid*block = 8,388,608 < 2^31: 32-bit index math is safe
    const int gid = blockIdx.x * blockDim.x + threadIdx.x;
    const int row = gid >> 15;                 // 2^15 threads per row
    const int col = (gid & 32767) << 2;        // element index within row

    const float* __restrict__ xr = x + (long long)row * COLS;

    // window needs elements [col-2, col+5]; v[k] = xr[col-2+k] with edge clamp
    float v[8];
    const vf4 cur = *(const vf4*)(xr + col);
    v[2] = cur.x; v[3] = cur.y; v[4] = cur.z; v[5] = cur.w;
    v[0] = xr[max(col - 2, 0)];                // L1 hits — halo cost negligible
    v[1] = xr[max(col - 1, 0)];
    v[6] = xr[min(col + 4, COLS - 1)];
    v[7] = xr[min(col + 5, COLS - 1)];

    float s_out[4], m_out[4];
#pragma unroll
    for (int k = 0; k < 4; ++k) {
        float p = v[k];
        p = fmaxf(p, v[k + 1]);
        p = fmaxf(p, v[k + 2]);
        p = fmaxf(p, v[k + 3]);
        p = fmaxf(p, v[k + 4]);
        const float xv   = v[k + 2];
        // precise expf on purpose: fast-math sigmoid risks flipping the
        // s >= thresh mask (single flip = 1.0 absmax fail); VALU hides
        // under memory time anyway.
        const float gate = 1.0f / (1.0f + expf(-SHARP * (xv - thresh)));
        const float lm   = 1.0f / (1.0f + expf(-SHARP * (xv - p)));
        const float s    = xv * gate * lm;
        s_out[k] = s;
        m_out[k] = (s >= thresh) ? 1.0f : 0.0f;
    }

    const long long base = (long long)row * COLS + col;
    *(vf4*)(smooth + base) = (vf4){ s_out[0], s_out[1], s_out[2], s_out[3] };
    *(vf4*)(mask + base)   = (vf4){ m_out[0], m_out[1], m_out[2], m_out[3] };
}

extern "C" void kernel_launch(void* const* d_in, const int* in_sizes, int n_in,
                              void* d_out, int out_size, void* d_ws, size_t ws_size,
                              hipStream_t stream) {
    const float* x            = (const float*)d_in[0];
    const float* logit_thresh = (const float*)d_in[1];

    float* smooth = (float*)d_out;
    float* mask   = (float*)d_out + (long long)ROWS * COLS;

    const long long n_thread = (long long)ROWS * COLS / 4;  // 8,388,608
    const int block = 256;
    const int grid  = (int)(n_thread / block);              // 32,768

    peak_extract_kernel<<<grid, block, 0, stream>>>(x, logit_thresh, smooth, mask);
}